// Round 17
// baseline (548.023 us; speedup 1.0000x reference)
//
#include <hip/hip_runtime.h>
#include <math.h>

#define S_LEN 512
#define B_SZ  256

typedef _Float16 f16x8 __attribute__((ext_vector_type(8)));
typedef _Float16 h2    __attribute__((ext_vector_type(2)));
typedef float    f32x4 __attribute__((ext_vector_type(4)));

__device__ __forceinline__ float sigm(float x) { return 1.0f / (1.0f + __expf(-x)); }

__device__ __forceinline__ float fdot2(h2 a, h2 b, float c) {
#if __has_builtin(__builtin_amdgcn_fdot2)
    return __builtin_amdgcn_fdot2(a, b, c, false);
#else
    return c + (float)a.x * (float)b.x + (float)a.y * (float)b.y;
#endif
}

// bit-reinterpret one float lane as a packed h2
#define H2C(f) __builtin_bit_cast(h2, f)
// 4 fdot2 along one float4(=4 h2) weight/act pair
#define DOT4(acc, W, H) do { \
    acc = fdot2(H2C((H).x), H2C((W).x), acc); \
    acc = fdot2(H2C((H).y), H2C((W).y), acc); \
    acc = fdot2(H2C((H).z), H2C((W).z), acc); \
    acc = fdot2(H2C((H).w), H2C((W).w), acc); } while (0)

// quad_perm butterfly adds
__device__ __forceinline__ float qsum1(float x) {   // xor 1
    int yi = __builtin_amdgcn_update_dpp(0, __builtin_bit_cast(int, x), 0xB1, 0xF, 0xF, true);
    return x + __builtin_bit_cast(float, yi);
}
__device__ __forceinline__ float qsum2(float x) {   // xor 2
    int yi = __builtin_amdgcn_update_dpp(0, __builtin_bit_cast(int, x), 0x4E, 0xF, 0xF, true);
    return x + __builtin_bit_cast(float, yi);
}

// raw barrier: drain LDS only; global loads/stores stay in flight
#define LBAR() do { \
    asm volatile("s_waitcnt lgkmcnt(0)" ::: "memory"); \
    __builtin_amdgcn_s_barrier(); \
    asm volatile("" ::: "memory"); \
} while (0)

// LDS tile byte offset with G4 XOR swizzle: row-major [128 rows][128 B]
__device__ __forceinline__ int swz(int row, int byte_in_row) {
    return row * 128 + (byte_in_row ^ ((row & 7) << 4));
}

// ---------------- pack: fp16 tables + packed weights + disc (fused, quad/row) -----
__global__ void k_pack16(const float* __restrict__ W1, const float* __restrict__ Wd,
                         const float* __restrict__ W2, const float* __restrict__ W3,
                         const float* __restrict__ W4, const float* __restrict__ b2,
                         const float* __restrict__ b3, const float* __restrict__ b4,
                         const float* __restrict__ h0, const float* __restrict__ Wa,
                         const float* __restrict__ Eq, const float* __restrict__ Eut,
                         const float* __restrict__ Eit,
                         const int* __restrict__ qseq, const float* __restrict__ Wdisc,
                         const float* __restrict__ bdisc,
                         _Float16* __restrict__ Eq16, _Float16* __restrict__ Eut16,
                         _Float16* __restrict__ Eit16,
                         _Float16* __restrict__ Wld16, _Float16* __restrict__ Wz16,
                         _Float16* __restrict__ Wa16, h2* __restrict__ Wsc,
                         float* __restrict__ bz, float* __restrict__ w1csum,
                         float* __restrict__ hcarry, float* __restrict__ pred,
                         float* __restrict__ discb)
{
    int idx0 = blockIdx.x * blockDim.x + threadIdx.x;
    int stride = gridDim.x * blockDim.x;
    for (int i = idx0; i < 10001 * 128; i += stride) Eq16[i] = (_Float16)Eq[i];
    for (int i = idx0; i < 1025 * 128; i += stride) Eut16[i] = (_Float16)Eut[i];
    for (int i = idx0; i < 1025 * 128; i += stride) Eit16[i] = (_Float16)Eit[i];
    for (int idx = idx0; idx < 256 * 256; idx += stride) {
        int c = idx >> 8, j = idx & 255;
        float v;
        if (c < 128) v = W1[c * 306 + j];
        else         v = (j < 128) ? Wd[(c - 128) * 128 + j] : 0.f;
        Wld16[idx] = (_Float16)v;
    }
    for (int idx = idx0; idx < 384 * 384; idx += stride) {
        int c = idx / 384, j = idx - c * 384;
        float v;
        if (c < 128)      v = W2[c * 512 + j];
        else if (c < 256) v = W3[(c - 128) * 512 + j];
        else              v = (j >= 128 && j < 256) ? W4[(c - 256) * 384 + 128 + j] : 0.f;
        Wz16[idx] = (_Float16)v;
    }
    for (int idx = idx0; idx < 128 * 128; idx += stride)
        Wa16[idx] = (_Float16)Wa[idx];
    // per-thread scan weights: slot = tid = k*2 + q (256 slots), 128 h2 each.
    for (int idx = idx0; idx < 256 * 128; idx += stride) {
        int slot = idx >> 7, e = idx & 127;
        int q = slot & 1, kk = slot >> 1;
        int grp = e >> 5;
        int j = q * 64 + (e & 31) * 2;
        const float* src;
        if (grp == 0)      src = W2 + kk * 512 + 384 + j;
        else if (grp == 1) src = W3 + kk * 512 + 384 + j;
        else if (grp == 2) src = W4 + kk * 384 + j;
        else               src = W4 + kk * 384 + 128 + j;
        h2 v; v.x = (_Float16)src[0]; v.y = (_Float16)src[1];
        Wsc[idx] = v;
    }
    for (int idx = idx0; idx < 384; idx += stride)
        bz[idx] = (idx < 128) ? b2[idx] : (idx < 256 ? b3[idx - 128] : b4[idx - 256]);
    for (int idx = idx0; idx < 128; idx += stride) {
        float s = 0.f;
        for (int j = 0; j < 50; ++j) s += W1[idx * 306 + 256 + j];
        w1csum[idx] = s;
    }
    for (int idx = idx0; idx < 256 * 128; idx += stride) hcarry[idx] = h0[idx];
    for (int idx = idx0; idx < 256; idx += stride) pred[(size_t)idx * S_LEN] = 0.f;
    // fused disc (quad-per-row, coalesced): 4 lanes handle one row, DPP reduce
    {
        float bds = bdisc[0];
        int r = idx0 >> 2;                     // 524288 threads / 4 = 131072 rows
        int q4 = idx0 & 3;
        if (r < 131072) {
            const float* qe = Eq + (size_t)qseq[r] * 128 + q4 * 32;
            const float* wd = Wdisc + q4 * 32;
            float s = 0.f;
#pragma unroll
            for (int j = 0; j < 32; ++j) s = fmaf(qe[j], wd[j], s);
            s = qsum2(qsum1(s));               // quad sum, all 4 lanes hold it
            if (q4 == 0) discb[r] = sigm(s + bds) * 10.0f;
        }
    }
}

// ---------------- MFMA GEMM 1: learn (cb=0) / diff (cb=1); K=256 ------------------
__global__ __launch_bounds__(256) void k_mm_ld(
    const int* __restrict__ qseq, const int* __restrict__ utseq, const int* __restrict__ cseq,
    const _Float16* __restrict__ Eq16, const _Float16* __restrict__ Eut16,
    const _Float16* __restrict__ Wld16, const float* __restrict__ b1,
    const float* __restrict__ bd, const float* __restrict__ w1csum,
    _Float16* __restrict__ learn16, _Float16* __restrict__ diff16,
    int s_lo, int out_row0)
{
    __shared__ _Float16 As[128 * 64];
    __shared__ _Float16 Bs[128 * 64];
    __shared__ int   ridxq[128];
    __shared__ int   ridxut[128];
    __shared__ float rcorr[128];
    __shared__ float cS[128];
    __shared__ float c2S[128];

    const int tid = threadIdx.x;
    const int vr0 = blockIdx.x * 128;
    const int cb = blockIdx.y;

    if (tid < 128) {
        int vr = vr0 + tid;
        int b = vr & 255, s = s_lo + (vr >> 8);
        int rin = b * S_LEN + s;
        ridxq[tid] = qseq[rin];
        ridxut[tid] = utseq[rin];
        rcorr[tid] = (float)cseq[rin];
        cS[tid] = (cb == 0) ? w1csum[tid] : 0.f;
        c2S[tid] = (cb == 0) ? b1[tid] : bd[tid];
    }
    __syncthreads();

    const int wid = tid >> 6, lane = tid & 63;
    const int wr = wid >> 1, wc = wid & 1;
    const int lrow = lane & 15, lkg = lane >> 4;
    const int arow = tid >> 1, apart = tid & 1;

    f32x4 acc[4][4];
#pragma unroll
    for (int i = 0; i < 4; ++i)
#pragma unroll
        for (int j = 0; j < 4; ++j) acc[i][j] = (f32x4){0.f, 0.f, 0.f, 0.f};

    for (int kb = 0; kb < 4; ++kb) {
        int k0 = kb * 64;
        const _Float16* srcA = (k0 < 128)
            ? (Eq16 + (size_t)ridxq[arow] * 128 + k0 + apart * 32)
            : (Eut16 + (size_t)ridxut[arow] * 128 + (k0 - 128) + apart * 32);
        const _Float16* srcB = Wld16 + (size_t)(cb * 128 + arow) * 256 + k0 + apart * 32;
#pragma unroll
        for (int j = 0; j < 4; ++j) {
            float4 va = *(const float4*)(srcA + j * 8);
            float4 vb = *(const float4*)(srcB + j * 8);
            int boff = apart * 64 + j * 16;
            *(float4*)((char*)As + swz(arow, boff)) = va;
            *(float4*)((char*)Bs + swz(arow, boff)) = vb;
        }
        __syncthreads();
#pragma unroll
        for (int ks = 0; ks < 2; ++ks) {
            f16x8 af[4], bf[4];
#pragma unroll
            for (int f = 0; f < 4; ++f) {
                int ar = wr * 64 + f * 16 + lrow;
                af[f] = *(const f16x8*)((const char*)As + swz(ar, ks * 64 + lkg * 16));
                int br = wc * 64 + f * 16 + lrow;
                bf[f] = *(const f16x8*)((const char*)Bs + swz(br, ks * 64 + lkg * 16));
            }
#pragma unroll
            for (int fi = 0; fi < 4; ++fi)
#pragma unroll
                for (int fj = 0; fj < 4; ++fj)
                    acc[fi][fj] = __builtin_amdgcn_mfma_f32_16x16x32_f16(
                        af[fi], bf[fj], acc[fi][fj], 0, 0, 0);
        }
        __syncthreads();
    }

    if (cb == 0) {
#pragma unroll
        for (int fi = 0; fi < 4; ++fi) {
#pragma unroll
            for (int r = 0; r < 4; ++r) {
                int lr_ = wr * 64 + fi * 16 + (lane >> 4) * 4 + r;
                int grow = vr0 + out_row0 + lr_;
                float corr = rcorr[lr_];
#pragma unroll
                for (int fj = 0; fj < 4; ++fj) {
                    int col = wc * 64 + fj * 16 + (lane & 15);
                    float v = acc[fi][fj][r] + corr * cS[col] + c2S[col];
                    learn16[(size_t)grow * 128 + col] = (_Float16)v;
                }
            }
        }
    } else {
#pragma unroll
        for (int fi = 0; fi < 4; ++fi) {
#pragma unroll
            for (int r = 0; r < 4; ++r) {
                int lr_ = wr * 64 + fi * 16 + (lane >> 4) * 4 + r;
                int grow = vr0 + out_row0 + lr_;
#pragma unroll
                for (int fj = 0; fj < 4; ++fj) {
                    int col = wc * 64 + fj * 16 + (lane & 15);
                    float v = sigm(acc[fi][fj][r] + c2S[col]);
                    diff16[(size_t)grow * 128 + col] = (_Float16)v;
                }
            }
        }
    }
}

// ---------------- MFMA GEMM 2: U16[ur, cb*128..] , K=384 --------------------------
__global__ __launch_bounds__(256) void k_mm_u(
    const int* __restrict__ itseq, const _Float16* __restrict__ Eit16,
    const _Float16* __restrict__ learn16, const _Float16* __restrict__ Wz16,
    const float* __restrict__ bz, _Float16* __restrict__ U16, int t0)
{
    __shared__ _Float16 As[128 * 64];
    __shared__ _Float16 Bs[128 * 64];
    __shared__ int   itidx[128];
    __shared__ float bzS[128];

    const int tid = threadIdx.x;
    const int ur0 = blockIdx.x * 128;
    const int cb = blockIdx.y;
    const int t = t0 + (ur0 >> 8);
    const bool tzero = (t == 0);

    if (tid < 128) {
        int b = (ur0 + tid) & 255;
        itidx[tid] = itseq[b * S_LEN + t];
        bzS[tid] = bz[cb * 128 + tid];
    }
    __syncthreads();

    const int wid = tid >> 6, lane = tid & 63;
    const int wr = wid >> 1, wc = wid & 1;
    const int lrow = lane & 15, lkg = lane >> 4;
    const int arow = tid >> 1, apart = tid & 1;

    f32x4 acc[4][4];
#pragma unroll
    for (int i = 0; i < 4; ++i)
#pragma unroll
        for (int j = 0; j < 4; ++j) acc[i][j] = (f32x4){0.f, 0.f, 0.f, 0.f};

    for (int kb = 0; kb < 6; ++kb) {
        int k0 = kb * 64;
        int sec = k0 >> 7;
        int off = (k0 & 127) + apart * 32;
        const _Float16* srcA;
        if (sec == 0)      srcA = tzero ? nullptr : (learn16 + (size_t)(ur0 + arow) * 128 + off);
        else if (sec == 1) srcA = Eit16 + (size_t)itidx[arow] * 128 + off;
        else               srcA = learn16 + (size_t)(ur0 + arow + 256) * 128 + off;
        const _Float16* srcB = Wz16 + (size_t)(cb * 128 + arow) * 384 + k0 + apart * 32;
#pragma unroll
        for (int j = 0; j < 4; ++j) {
            float4 va;
            if (srcA) va = *(const float4*)(srcA + j * 8);
            else { va.x = va.y = va.z = va.w = 0.f; }
            float4 vb = *(const float4*)(srcB + j * 8);
            int boff = apart * 64 + j * 16;
            *(float4*)((char*)As + swz(arow, boff)) = va;
            *(float4*)((char*)Bs + swz(arow, boff)) = vb;
        }
        __syncthreads();
#pragma unroll
        for (int ks = 0; ks < 2; ++ks) {
            f16x8 af[4], bf[4];
#pragma unroll
            for (int f = 0; f < 4; ++f) {
                int ar = wr * 64 + f * 16 + lrow;
                af[f] = *(const f16x8*)((const char*)As + swz(ar, ks * 64 + lkg * 16));
                int br = wc * 64 + f * 16 + lrow;
                bf[f] = *(const f16x8*)((const char*)Bs + swz(br, ks * 64 + lkg * 16));
            }
#pragma unroll
            for (int fi = 0; fi < 4; ++fi)
#pragma unroll
                for (int fj = 0; fj < 4; ++fj)
                    acc[fi][fj] = __builtin_amdgcn_mfma_f32_16x16x32_f16(
                        af[fi], bf[fj], acc[fi][fj], 0, 0, 0);
        }
        __syncthreads();
    }

#pragma unroll
    for (int fi = 0; fi < 4; ++fi) {
#pragma unroll
        for (int r = 0; r < 4; ++r) {
            int lr_ = wr * 64 + fi * 16 + (lane >> 4) * 4 + r;
            int grow = ur0 + lr_;
#pragma unroll
            for (int fj = 0; fj < 4; ++fj) {
                int col = wc * 64 + fj * 16 + (lane & 15);
                float v = acc[fi][fj][r] + bzS[col];
                U16[(size_t)grow * 384 + cb * 128 + col] = (_Float16)v;
            }
        }
    }
}

// ---------------- scan v14: R16 + 4-way ILP dot chains ----------------------------
__global__ __launch_bounds__(256) __attribute__((amdgpu_waves_per_eu(1, 1)))
void k_scan(_Float16* __restrict__ U16, float* __restrict__ hcarry,
            const h2* __restrict__ Wsc, int T_len)
{
    const int b = blockIdx.x;
    const int tid = threadIdx.x;
    const int k = tid >> 1;          // output channel 0..127
    const int q = tid & 1;           // j-half (64 elems = 32 h2)

    // 128 h2 of weights in 32 NAMED float4 locals (no arrays -> no scratch)
    const float4* wsrc = (const float4*)(Wsc + (size_t)tid * 128);
    float4 wA0 = wsrc[0],  wA1 = wsrc[1],  wA2 = wsrc[2],  wA3 = wsrc[3];
    float4 wA4 = wsrc[4],  wA5 = wsrc[5],  wA6 = wsrc[6],  wA7 = wsrc[7];   // W2h
    float4 wB0 = wsrc[8],  wB1 = wsrc[9],  wB2 = wsrc[10], wB3 = wsrc[11];
    float4 wB4 = wsrc[12], wB5 = wsrc[13], wB6 = wsrc[14], wB7 = wsrc[15];  // W3h
    float4 wC0 = wsrc[16], wC1 = wsrc[17], wC2 = wsrc[18], wC3 = wsrc[19];
    float4 wC4 = wsrc[20], wC5 = wsrc[21], wC6 = wsrc[22], wC7 = wsrc[23];  // W4h
    float4 wD0 = wsrc[24], wD1 = wsrc[25], wD2 = wsrc[26], wD3 = wsrc[27];
    float4 wD4 = wsrc[28], wD5 = wsrc[29], wD6 = wsrc[30], wD7 = wsrc[31];  // W4l

    __shared__ float4 hpv[16];   // 128 halfs of h
    __shared__ float4 lgv[16];   // 128 halfs of LG

    float h_k = hcarry[b * 128 + k];   // f32 carried state on both lanes of the pair
    if (tid < 64) {
        h2 v;
        v.x = (_Float16)hcarry[b * 128 + 2 * tid];
        v.y = (_Float16)hcarry[b * 128 + 2 * tid + 1];
        ((h2*)hpv)[tid] = v;
    }
    __syncthreads();

    const size_t Ustep = (size_t)B_SZ * 384;
    _Float16* Ub = U16 + (size_t)b * 384;
    const _Float16* Upf = Ub + Ustep;
    _Float16* Ust = Ub + k;            // q==1 lanes store h here each step
    float u2c = (float)Ub[k], u3c = (float)Ub[128 + k], u4c = (float)Ub[256 + k];

#define SCAN_STAGE1()                                                                \
        float4 hq0 = hpv[q * 8 + 0], hq1 = hpv[q * 8 + 1],                           \
               hq2 = hpv[q * 8 + 2], hq3 = hpv[q * 8 + 3],                           \
               hq4 = hpv[q * 8 + 4], hq5 = hpv[q * 8 + 5],                           \
               hq6 = hpv[q * 8 + 6], hq7 = hpv[q * 8 + 7];                           \
        float s2a = 0.f, s2b = 0.f, s2c = 0.f, s2d = 0.f;                            \
        float s3a = 0.f, s3b = 0.f, s3c = 0.f, s3d = 0.f;                            \
        float s4a = 0.f, s4b = 0.f, s4c = 0.f, s4d = 0.f;                            \
        DOT4(s2a, wA0, hq0); DOT4(s2b, wA1, hq1); DOT4(s2c, wA2, hq2); DOT4(s2d, wA3, hq3); \
        DOT4(s2a, wA4, hq4); DOT4(s2b, wA5, hq5); DOT4(s2c, wA6, hq6); DOT4(s2d, wA7, hq7); \
        DOT4(s3a, wB0, hq0); DOT4(s3b, wB1, hq1); DOT4(s3c, wB2, hq2); DOT4(s3d, wB3, hq3); \
        DOT4(s3a, wB4, hq4); DOT4(s3b, wB5, hq5); DOT4(s3c, wB6, hq6); DOT4(s3d, wB7, hq7); \
        DOT4(s4a, wC0, hq0); DOT4(s4b, wC1, hq1); DOT4(s4c, wC2, hq2); DOT4(s4d, wC3, hq3); \
        DOT4(s4a, wC4, hq4); DOT4(s4b, wC5, hq5); DOT4(s4c, wC6, hq6); DOT4(s4d, wC7, hq7); \
        float s2 = qsum1((s2a + s2b) + (s2c + s2d));                                 \
        float s3 = qsum1((s3a + s3b) + (s3c + s3d));                                 \
        float s4 = qsum1((s4a + s4b) + (s4c + s4d));                                 \
        float LG_k = sigm(s3 + u3c) * sigm(2.f * (s2 + u2c));                        \
        if (q == 0) ((_Float16*)lgv)[k] = (_Float16)LG_k;                            \
        LBAR();

#define SCAN_STAGE2()                                                                \
        float4 lq0 = lgv[q * 8 + 0], lq1 = lgv[q * 8 + 1],                           \
               lq2 = lgv[q * 8 + 2], lq3 = lgv[q * 8 + 3];                           \
        float4 lq4 = lgv[q * 8 + 4], lq5 = lgv[q * 8 + 5],                           \
               lq6 = lgv[q * 8 + 6], lq7 = lgv[q * 8 + 7];                           \
        float sLa = 0.f, sLb = 0.f, sLc = 0.f, sLd = 0.f;                            \
        DOT4(sLa, wD0, lq0); DOT4(sLb, wD1, lq1); DOT4(sLc, wD2, lq2); DOT4(sLd, wD3, lq3); \
        DOT4(sLa, wD4, lq4); DOT4(sLb, wD5, lq5); DOT4(sLc, wD6, lq6); DOT4(sLd, wD7, lq7); \
        float s4l = qsum1((sLa + sLb) + (sLc + sLd));                                \
        float gf = sigm(s4 + s4l + u4c);                                             \
        h_k = LG_k + gf * h_k;                                                       \
        if (q == 0) ((_Float16*)hpv)[k] = (_Float16)h_k;                             \
        if (q == 1) *Ust = (_Float16)h_k;                                            \
        LBAR();

    for (int lt = 0; lt < T_len - 1; ++lt) {
        // unconditional prefetch via carried pointer
        float u2n = (float)Upf[k];
        float u3n = (float)Upf[128 + k];
        float u4n = (float)Upf[256 + k];

        { SCAN_STAGE1() SCAN_STAGE2() }

        Ust += Ustep; Upf += Ustep;
        u2c = u2n; u3c = u3n; u4c = u4n;
    }
    // peeled final iteration (no prefetch)
    { SCAN_STAGE1() SCAN_STAGE2() }

#undef SCAN_STAGE1
#undef SCAN_STAGE2

    if (q == 0) hcarry[b * 128 + k] = h_k;
}

// ---------------- MFMA GEMM 3 + fused readout: ability/term/y ---------------------
__global__ __launch_bounds__(256) void k_mm_a(
    const _Float16* __restrict__ U16, const _Float16* __restrict__ diff16,
    const float* __restrict__ disc, const _Float16* __restrict__ Wa16,
    const float* __restrict__ ba, float* __restrict__ pred, int t0)
{
    __shared__ _Float16 smem[2][128 * 64];   // A/B tiles; later d-tile [128][128]
    __shared__ float redbuf[128][2];
    __shared__ float baS[128];
    __shared__ float gS[128];

    const int tid = threadIdx.x;
    const int ur0 = blockIdx.x * 128;
    const int lt = ur0 >> 8;
    _Float16* As = smem[0];
    _Float16* Bs = smem[1];

    if (tid < 128) {
        baS[tid] = ba[tid];
        int r = ur0 + tid;
        int b = r & 255;
        gS[tid] = disc[b * S_LEN + t0 + lt + 1];
    }

    const int wid = tid >> 6, lane = tid & 63;
    const int wr = wid >> 1, wc = wid & 1;
    const int lrow = lane & 15, lkg = lane >> 4;
    const int arow = tid >> 1, apart = tid & 1;

    f32x4 acc[4][4];
#pragma unroll
    for (int i = 0; i < 4; ++i)
#pragma unroll
        for (int j = 0; j < 4; ++j) acc[i][j] = (f32x4){0.f, 0.f, 0.f, 0.f};

    for (int kb = 0; kb < 2; ++kb) {
        int k0 = kb * 64;
        const _Float16* srcA = U16 + (size_t)(ur0 + arow) * 384 + k0 + apart * 32;
        const _Float16* srcB = Wa16 + (size_t)arow * 128 + k0 + apart * 32;
#pragma unroll
        for (int j = 0; j < 4; ++j) {
            float4 va = *(const float4*)(srcA + j * 8);
            float4 vb = *(const float4*)(srcB + j * 8);
            int boff = apart * 64 + j * 16;
            *(float4*)((char*)As + swz(arow, boff)) = va;
            *(float4*)((char*)Bs + swz(arow, boff)) = vb;
        }
        __syncthreads();
#pragma unroll
        for (int ks = 0; ks < 2; ++ks) {
            f16x8 af[4], bf[4];
#pragma unroll
            for (int f = 0; f < 4; ++f) {
                int ar = wr * 64 + f * 16 + lrow;
                af[f] = *(const f16x8*)((const char*)As + swz(ar, ks * 64 + lkg * 16));
                int br = wc * 64 + f * 16 + lrow;
                bf[f] = *(const f16x8*)((const char*)Bs + swz(br, ks * 64 + lkg * 16));
            }
#pragma unroll
            for (int fi = 0; fi < 4; ++fi)
#pragma unroll
                for (int fj = 0; fj < 4; ++fj)
                    acc[fi][fj] = __builtin_amdgcn_mfma_f32_16x16x32_f16(
                        af[fi], bf[fj], acc[fi][fj], 0, 0, 0);
        }
        __syncthreads();
    }

    // stage d tile [128 rows][128 cols] into smem (32 KB, coalesced)
    {
        const float4* dsrc = (const float4*)(diff16 + (size_t)(ur0 + 512) * 128);
        float4* ddst = (float4*)smem;
        for (int i = tid; i < 2048; i += 256) ddst[i] = dsrc[i];
    }
    __syncthreads();

    const _Float16* dtile = (const _Float16*)smem;
#pragma unroll
    for (int fi = 0; fi < 4; ++fi) {
#pragma unroll
        for (int rr = 0; rr < 4; ++rr) {
            int row = wr * 64 + fi * 16 + (lane >> 4) * 4 + rr;
            float part = 0.f;
#pragma unroll
            for (int fj = 0; fj < 4; ++fj) {
                int col = wc * 64 + fj * 16 + (lane & 15);
                float d = (float)dtile[row * 128 + col];
                float ab = sigm(acc[fi][fj][rr] + baS[col]);
                part += (ab - d) * d;
            }
            part += __shfl_xor(part, 1, 64);
            part += __shfl_xor(part, 2, 64);
            part += __shfl_xor(part, 4, 64);
            part += __shfl_xor(part, 8, 64);
            if ((lane & 15) == 0) redbuf[row][wc] = part;
        }
    }
    __syncthreads();
    if (tid < 128) {
        int r = ur0 + tid;
        int b = r & 255;
        float v = redbuf[tid][0] + redbuf[tid][1];
        pred[(size_t)b * S_LEN + t0 + lt + 1] = sigm(gS[tid] * v);
    }
}

extern "C" void kernel_launch(void* const* d_in, const int* in_sizes, int n_in,
                              void* d_out, int out_size, void* d_ws, size_t ws_size,
                              hipStream_t stream)
{
    const int*   qseq  = (const int*)d_in[0];
    const int*   itseq = (const int*)d_in[1];
    const int*   utseq = (const int*)d_in[2];
    const int*   cseq  = (const int*)d_in[3];
    const float* h0    = (const float*)d_in[4];
    const float* Eq    = (const float*)d_in[5];
    const float* Eut   = (const float*)d_in[6];
    const float* Eit   = (const float*)d_in[7];
    const float* W1    = (const float*)d_in[8];
    const float* b1    = (const float*)d_in[9];
    const float* W2    = (const float*)d_in[10];
    const float* b2    = (const float*)d_in[11];
    const float* W3    = (const float*)d_in[12];
    const float* b3    = (const float*)d_in[13];
    const float* W4    = (const float*)d_in[14];
    const float* b4    = (const float*)d_in[15];
    const float* Wa    = (const float*)d_in[16];
    const float* ba    = (const float*)d_in[17];
    const float* Wd    = (const float*)d_in[18];
    const float* bd    = (const float*)d_in[19];
    const float* Wdisc = (const float*)d_in[20];
    const float* bdisc = (const float*)d_in[21];
    float* pred = (float*)d_out;

    // --- fixed-region layout ---
    char* p = (char*)d_ws;
    float* bz      = (float*)p;           p += 384 * 4;
    float* w1csum  = (float*)p;           p += 128 * 4;
    float* discb   = (float*)p;           p += 131072 * 4;
    float* hcarry  = (float*)p;           p += 32768 * 4;
    _Float16* Eq16  = (_Float16*)p;       p += 10001 * 128 * 2;
    _Float16* Eut16 = (_Float16*)p;       p += 1025 * 128 * 2;
    _Float16* Eit16 = (_Float16*)p;       p += 1025 * 128 * 2;
    _Float16* Wld16 = (_Float16*)p;       p += 256 * 256 * 2;
    _Float16* Wz16  = (_Float16*)p;       p += 384 * 384 * 2;
    _Float16* Wa16  = (_Float16*)p;       p += 128 * 128 * 2;
    h2*       Wsc   = (h2*)p;             p += 256 * 128 * 4;   // 128 KB
    const size_t fixed_bytes = (size_t)(p - (char*)d_ws);

    int T_CH = 4;
    {
        const int cands[8] = {511, 256, 128, 64, 32, 16, 8, 4};
        for (int ci = 0; ci < 8; ++ci) {
            size_t T = (size_t)cands[ci];
            size_t need = fixed_bytes + (T + 2) * 131072 + T * 196608;
            if (need <= ws_size) { T_CH = cands[ci]; break; }
        }
    }
    _Float16* learn16 = (_Float16*)p;     p += (size_t)(T_CH + 2) * 65536 * 2;
    _Float16* diff16  = (_Float16*)p;     p += (size_t)(T_CH + 2) * 65536 * 2;
    _Float16* U16     = (_Float16*)p;

    k_pack16<<<2048, 256, 0, stream>>>(W1, Wd, W2, W3, W4, b2, b3, b4, h0, Wa,
                                       Eq, Eut, Eit, qseq, Wdisc, bdisc,
                                       Eq16, Eut16, Eit16, Wld16, Wz16, Wa16, Wsc,
                                       bz, w1csum, hcarry, pred, discb);

    for (int t0 = 0; t0 < S_LEN - 1; t0 += T_CH) {
        int T_len = S_LEN - 1 - t0; if (T_len > T_CH) T_len = T_CH;
        int s_lo = (t0 == 0) ? 0 : (t0 - 1);
        int s_hi = t0 + T_len + 1;
        int out_row0 = (s_lo - (t0 - 1)) * 256;
        k_mm_ld<<<dim3((s_hi - s_lo) * 2, 2), 256, 0, stream>>>(
            qseq, utseq, cseq, Eq16, Eut16, Wld16, b1, bd, w1csum,
            learn16, diff16, s_lo, out_row0);
        k_mm_u<<<dim3(T_len * 2, 3), 256, 0, stream>>>(
            itseq, Eit16, learn16, Wz16, bz, U16, t0);
        k_scan<<<256, 256, 0, stream>>>(U16, hcarry, Wsc, T_len);
        k_mm_a<<<T_len * 2, 256, 0, stream>>>(U16, diff16, discb, Wa16, ba, pred, t0);
    }
}

// Round 18
// 531.730 us; speedup vs baseline: 1.0306x; 1.0306x over previous
//
#include <hip/hip_runtime.h>
#include <math.h>

#define S_LEN 512
#define B_SZ  256

typedef _Float16 f16x8 __attribute__((ext_vector_type(8)));
typedef _Float16 h2    __attribute__((ext_vector_type(2)));
typedef float    f32x4 __attribute__((ext_vector_type(4)));

__device__ __forceinline__ float sigm(float x) { return 1.0f / (1.0f + __expf(-x)); }

__device__ __forceinline__ float fdot2(h2 a, h2 b, float c) {
#if __has_builtin(__builtin_amdgcn_fdot2)
    return __builtin_amdgcn_fdot2(a, b, c, false);
#else
    return c + (float)a.x * (float)b.x + (float)a.y * (float)b.y;
#endif
}

// bit-reinterpret one float lane as a packed h2
#define H2C(f) __builtin_bit_cast(h2, f)
// 4 fdot2 along one float4(=4 h2) weight/act pair
#define DOT4(acc, W, H) do { \
    acc = fdot2(H2C((H).x), H2C((W).x), acc); \
    acc = fdot2(H2C((H).y), H2C((W).y), acc); \
    acc = fdot2(H2C((H).z), H2C((W).z), acc); \
    acc = fdot2(H2C((H).w), H2C((W).w), acc); } while (0)

// quad_perm butterfly add, xor-1 only: both lanes of a pair hold the pair sum.
__device__ __forceinline__ float qsum1(float x) {
    int yi = __builtin_amdgcn_update_dpp(0, __builtin_bit_cast(int, x), 0xB1, 0xF, 0xF, true);
    return x + __builtin_bit_cast(float, yi);
}

// raw barrier: drain LDS only; global loads/stores stay in flight
#define LBAR() do { \
    asm volatile("s_waitcnt lgkmcnt(0)" ::: "memory"); \
    __builtin_amdgcn_s_barrier(); \
    asm volatile("" ::: "memory"); \
} while (0)

// LDS tile byte offset with G4 XOR swizzle: row-major [128 rows][128 B]
__device__ __forceinline__ int swz(int row, int byte_in_row) {
    return row * 128 + (byte_in_row ^ ((row & 7) << 4));
}

// ---------------- pack: fp16 tables + packed weights + disc (fused) ---------------
__global__ void k_pack16(const float* __restrict__ W1, const float* __restrict__ Wd,
                         const float* __restrict__ W2, const float* __restrict__ W3,
                         const float* __restrict__ W4, const float* __restrict__ b2,
                         const float* __restrict__ b3, const float* __restrict__ b4,
                         const float* __restrict__ h0, const float* __restrict__ Wa,
                         const float* __restrict__ Eq, const float* __restrict__ Eut,
                         const float* __restrict__ Eit,
                         const int* __restrict__ qseq, const float* __restrict__ Wdisc,
                         const float* __restrict__ bdisc,
                         _Float16* __restrict__ Eq16, _Float16* __restrict__ Eut16,
                         _Float16* __restrict__ Eit16,
                         _Float16* __restrict__ Wld16, _Float16* __restrict__ Wz16,
                         _Float16* __restrict__ Wa16, h2* __restrict__ Wsc,
                         float* __restrict__ bz, float* __restrict__ w1csum,
                         float* __restrict__ hcarry, float* __restrict__ pred,
                         float* __restrict__ discb)
{
    int idx0 = blockIdx.x * blockDim.x + threadIdx.x;
    int stride = gridDim.x * blockDim.x;
    for (int i = idx0; i < 10001 * 128; i += stride) Eq16[i] = (_Float16)Eq[i];
    for (int i = idx0; i < 1025 * 128; i += stride) Eut16[i] = (_Float16)Eut[i];
    for (int i = idx0; i < 1025 * 128; i += stride) Eit16[i] = (_Float16)Eit[i];
    for (int idx = idx0; idx < 256 * 256; idx += stride) {
        int c = idx >> 8, j = idx & 255;
        float v;
        if (c < 128) v = W1[c * 306 + j];
        else         v = (j < 128) ? Wd[(c - 128) * 128 + j] : 0.f;
        Wld16[idx] = (_Float16)v;
    }
    for (int idx = idx0; idx < 384 * 384; idx += stride) {
        int c = idx / 384, j = idx - c * 384;
        float v;
        if (c < 128)      v = W2[c * 512 + j];
        else if (c < 256) v = W3[(c - 128) * 512 + j];
        else              v = (j >= 128 && j < 256) ? W4[(c - 256) * 384 + 128 + j] : 0.f;
        Wz16[idx] = (_Float16)v;
    }
    for (int idx = idx0; idx < 128 * 128; idx += stride)
        Wa16[idx] = (_Float16)Wa[idx];
    // per-thread scan weights: slot = tid = k*2 + q (256 slots), 128 h2 each.
    for (int idx = idx0; idx < 256 * 128; idx += stride) {
        int slot = idx >> 7, e = idx & 127;
        int q = slot & 1, kk = slot >> 1;
        int grp = e >> 5;
        int j = q * 64 + (e & 31) * 2;
        const float* src;
        if (grp == 0)      src = W2 + kk * 512 + 384 + j;
        else if (grp == 1) src = W3 + kk * 512 + 384 + j;
        else if (grp == 2) src = W4 + kk * 384 + j;
        else               src = W4 + kk * 384 + 128 + j;
        h2 v; v.x = (_Float16)src[0]; v.y = (_Float16)src[1];
        Wsc[idx] = v;
    }
    for (int idx = idx0; idx < 384; idx += stride)
        bz[idx] = (idx < 128) ? b2[idx] : (idx < 256 ? b3[idx - 128] : b4[idx - 256]);
    for (int idx = idx0; idx < 128; idx += stride) {
        float s = 0.f;
        for (int j = 0; j < 50; ++j) s += W1[idx * 306 + 256 + j];
        w1csum[idx] = s;
    }
    for (int idx = idx0; idx < 256 * 128; idx += stride) hcarry[idx] = h0[idx];
    for (int idx = idx0; idx < 256; idx += stride) pred[(size_t)idx * S_LEN] = 0.f;
    // fused disc: sigmoid(q_emb . Wdisc + bdisc) * 10 for all 131072 rows
    {
        float bds = bdisc[0];
        for (int r = idx0; r < 131072; r += stride) {
            const float* qe = Eq + (size_t)qseq[r] * 128;
            float s = 0.f;
            for (int j = 0; j < 128; ++j) s = fmaf(qe[j], Wdisc[j], s);
            discb[r] = sigm(s + bds) * 10.0f;
        }
    }
}

// ---------------- MFMA GEMM 1: learn (cb=0) / diff (cb=1); K=256 ------------------
__global__ __launch_bounds__(256) void k_mm_ld(
    const int* __restrict__ qseq, const int* __restrict__ utseq, const int* __restrict__ cseq,
    const _Float16* __restrict__ Eq16, const _Float16* __restrict__ Eut16,
    const _Float16* __restrict__ Wld16, const float* __restrict__ b1,
    const float* __restrict__ bd, const float* __restrict__ w1csum,
    _Float16* __restrict__ learn16, _Float16* __restrict__ diff16,
    int s_lo, int out_row0)
{
    __shared__ _Float16 As[128 * 64];
    __shared__ _Float16 Bs[128 * 64];
    __shared__ int   ridxq[128];
    __shared__ int   ridxut[128];
    __shared__ float rcorr[128];
    __shared__ float cS[128];
    __shared__ float c2S[128];

    const int tid = threadIdx.x;
    const int vr0 = blockIdx.x * 128;
    const int cb = blockIdx.y;

    if (tid < 128) {
        int vr = vr0 + tid;
        int b = vr & 255, s = s_lo + (vr >> 8);
        int rin = b * S_LEN + s;
        ridxq[tid] = qseq[rin];
        ridxut[tid] = utseq[rin];
        rcorr[tid] = (float)cseq[rin];
        cS[tid] = (cb == 0) ? w1csum[tid] : 0.f;
        c2S[tid] = (cb == 0) ? b1[tid] : bd[tid];
    }
    __syncthreads();

    const int wid = tid >> 6, lane = tid & 63;
    const int wr = wid >> 1, wc = wid & 1;
    const int lrow = lane & 15, lkg = lane >> 4;
    const int arow = tid >> 1, apart = tid & 1;

    f32x4 acc[4][4];
#pragma unroll
    for (int i = 0; i < 4; ++i)
#pragma unroll
        for (int j = 0; j < 4; ++j) acc[i][j] = (f32x4){0.f, 0.f, 0.f, 0.f};

    for (int kb = 0; kb < 4; ++kb) {
        int k0 = kb * 64;
        const _Float16* srcA = (k0 < 128)
            ? (Eq16 + (size_t)ridxq[arow] * 128 + k0 + apart * 32)
            : (Eut16 + (size_t)ridxut[arow] * 128 + (k0 - 128) + apart * 32);
        const _Float16* srcB = Wld16 + (size_t)(cb * 128 + arow) * 256 + k0 + apart * 32;
#pragma unroll
        for (int j = 0; j < 4; ++j) {
            float4 va = *(const float4*)(srcA + j * 8);
            float4 vb = *(const float4*)(srcB + j * 8);
            int boff = apart * 64 + j * 16;
            *(float4*)((char*)As + swz(arow, boff)) = va;
            *(float4*)((char*)Bs + swz(arow, boff)) = vb;
        }
        __syncthreads();
#pragma unroll
        for (int ks = 0; ks < 2; ++ks) {
            f16x8 af[4], bf[4];
#pragma unroll
            for (int f = 0; f < 4; ++f) {
                int ar = wr * 64 + f * 16 + lrow;
                af[f] = *(const f16x8*)((const char*)As + swz(ar, ks * 64 + lkg * 16));
                int br = wc * 64 + f * 16 + lrow;
                bf[f] = *(const f16x8*)((const char*)Bs + swz(br, ks * 64 + lkg * 16));
            }
#pragma unroll
            for (int fi = 0; fi < 4; ++fi)
#pragma unroll
                for (int fj = 0; fj < 4; ++fj)
                    acc[fi][fj] = __builtin_amdgcn_mfma_f32_16x16x32_f16(
                        af[fi], bf[fj], acc[fi][fj], 0, 0, 0);
        }
        __syncthreads();
    }

    if (cb == 0) {
#pragma unroll
        for (int fi = 0; fi < 4; ++fi) {
#pragma unroll
            for (int r = 0; r < 4; ++r) {
                int lr_ = wr * 64 + fi * 16 + (lane >> 4) * 4 + r;
                int grow = vr0 + out_row0 + lr_;
                float corr = rcorr[lr_];
#pragma unroll
                for (int fj = 0; fj < 4; ++fj) {
                    int col = wc * 64 + fj * 16 + (lane & 15);
                    float v = acc[fi][fj][r] + corr * cS[col] + c2S[col];
                    learn16[(size_t)grow * 128 + col] = (_Float16)v;
                }
            }
        }
    } else {
#pragma unroll
        for (int fi = 0; fi < 4; ++fi) {
#pragma unroll
            for (int r = 0; r < 4; ++r) {
                int lr_ = wr * 64 + fi * 16 + (lane >> 4) * 4 + r;
                int grow = vr0 + out_row0 + lr_;
#pragma unroll
                for (int fj = 0; fj < 4; ++fj) {
                    int col = wc * 64 + fj * 16 + (lane & 15);
                    float v = sigm(acc[fi][fj][r] + c2S[col]);
                    diff16[(size_t)grow * 128 + col] = (_Float16)v;
                }
            }
        }
    }
}

// ---------------- MFMA GEMM 2: U16[ur, cb*128..] , K=384 --------------------------
__global__ __launch_bounds__(256) void k_mm_u(
    const int* __restrict__ itseq, const _Float16* __restrict__ Eit16,
    const _Float16* __restrict__ learn16, const _Float16* __restrict__ Wz16,
    const float* __restrict__ bz, _Float16* __restrict__ U16, int t0)
{
    __shared__ _Float16 As[128 * 64];
    __shared__ _Float16 Bs[128 * 64];
    __shared__ int   itidx[128];
    __shared__ float bzS[128];

    const int tid = threadIdx.x;
    const int ur0 = blockIdx.x * 128;
    const int cb = blockIdx.y;
    const int t = t0 + (ur0 >> 8);
    const bool tzero = (t == 0);

    if (tid < 128) {
        int b = (ur0 + tid) & 255;
        itidx[tid] = itseq[b * S_LEN + t];
        bzS[tid] = bz[cb * 128 + tid];
    }
    __syncthreads();

    const int wid = tid >> 6, lane = tid & 63;
    const int wr = wid >> 1, wc = wid & 1;
    const int lrow = lane & 15, lkg = lane >> 4;
    const int arow = tid >> 1, apart = tid & 1;

    f32x4 acc[4][4];
#pragma unroll
    for (int i = 0; i < 4; ++i)
#pragma unroll
        for (int j = 0; j < 4; ++j) acc[i][j] = (f32x4){0.f, 0.f, 0.f, 0.f};

    for (int kb = 0; kb < 6; ++kb) {
        int k0 = kb * 64;
        int sec = k0 >> 7;
        int off = (k0 & 127) + apart * 32;
        const _Float16* srcA;
        if (sec == 0)      srcA = tzero ? nullptr : (learn16 + (size_t)(ur0 + arow) * 128 + off);
        else if (sec == 1) srcA = Eit16 + (size_t)itidx[arow] * 128 + off;
        else               srcA = learn16 + (size_t)(ur0 + arow + 256) * 128 + off;
        const _Float16* srcB = Wz16 + (size_t)(cb * 128 + arow) * 384 + k0 + apart * 32;
#pragma unroll
        for (int j = 0; j < 4; ++j) {
            float4 va;
            if (srcA) va = *(const float4*)(srcA + j * 8);
            else { va.x = va.y = va.z = va.w = 0.f; }
            float4 vb = *(const float4*)(srcB + j * 8);
            int boff = apart * 64 + j * 16;
            *(float4*)((char*)As + swz(arow, boff)) = va;
            *(float4*)((char*)Bs + swz(arow, boff)) = vb;
        }
        __syncthreads();
#pragma unroll
        for (int ks = 0; ks < 2; ++ks) {
            f16x8 af[4], bf[4];
#pragma unroll
            for (int f = 0; f < 4; ++f) {
                int ar = wr * 64 + f * 16 + lrow;
                af[f] = *(const f16x8*)((const char*)As + swz(ar, ks * 64 + lkg * 16));
                int br = wc * 64 + f * 16 + lrow;
                bf[f] = *(const f16x8*)((const char*)Bs + swz(br, ks * 64 + lkg * 16));
            }
#pragma unroll
            for (int fi = 0; fi < 4; ++fi)
#pragma unroll
                for (int fj = 0; fj < 4; ++fj)
                    acc[fi][fj] = __builtin_amdgcn_mfma_f32_16x16x32_f16(
                        af[fi], bf[fj], acc[fi][fj], 0, 0, 0);
        }
        __syncthreads();
    }

#pragma unroll
    for (int fi = 0; fi < 4; ++fi) {
#pragma unroll
        for (int r = 0; r < 4; ++r) {
            int lr_ = wr * 64 + fi * 16 + (lane >> 4) * 4 + r;
            int grow = ur0 + lr_;
#pragma unroll
            for (int fj = 0; fj < 4; ++fj) {
                int col = wc * 64 + fj * 16 + (lane & 15);
                float v = acc[fi][fj][r] + bzS[col];
                U16[(size_t)grow * 384 + cb * 128 + col] = (_Float16)v;
            }
        }
    }
}

// ---------------- scan v13: R12 + pointer-incremented prefetch/store, peeled tail -
__global__ __launch_bounds__(256) __attribute__((amdgpu_waves_per_eu(1, 1)))
void k_scan(_Float16* __restrict__ U16, float* __restrict__ hcarry,
            const h2* __restrict__ Wsc, int T_len)
{
    const int b = blockIdx.x;
    const int tid = threadIdx.x;
    const int k = tid >> 1;          // output channel 0..127
    const int q = tid & 1;           // j-half (64 elems = 32 h2)

    // 128 h2 of weights in 32 NAMED float4 locals (no arrays -> no scratch)
    const float4* wsrc = (const float4*)(Wsc + (size_t)tid * 128);
    float4 wA0 = wsrc[0],  wA1 = wsrc[1],  wA2 = wsrc[2],  wA3 = wsrc[3];
    float4 wA4 = wsrc[4],  wA5 = wsrc[5],  wA6 = wsrc[6],  wA7 = wsrc[7];   // W2h
    float4 wB0 = wsrc[8],  wB1 = wsrc[9],  wB2 = wsrc[10], wB3 = wsrc[11];
    float4 wB4 = wsrc[12], wB5 = wsrc[13], wB6 = wsrc[14], wB7 = wsrc[15];  // W3h
    float4 wC0 = wsrc[16], wC1 = wsrc[17], wC2 = wsrc[18], wC3 = wsrc[19];
    float4 wC4 = wsrc[20], wC5 = wsrc[21], wC6 = wsrc[22], wC7 = wsrc[23];  // W4h
    float4 wD0 = wsrc[24], wD1 = wsrc[25], wD2 = wsrc[26], wD3 = wsrc[27];
    float4 wD4 = wsrc[28], wD5 = wsrc[29], wD6 = wsrc[30], wD7 = wsrc[31];  // W4l

    __shared__ float4 hpv[16];   // 128 halfs of h
    __shared__ float4 lgv[16];   // 128 halfs of LG

    float h_k = hcarry[b * 128 + k];   // f32 carried state on both lanes of the pair
    if (tid < 64) {
        h2 v;
        v.x = (_Float16)hcarry[b * 128 + 2 * tid];
        v.y = (_Float16)hcarry[b * 128 + 2 * tid + 1];
        ((h2*)hpv)[tid] = v;
    }
    __syncthreads();

    const size_t Ustep = (size_t)B_SZ * 384;
    _Float16* Ub = U16 + (size_t)b * 384;
    // pointer-carried addressing: prefetch ptr (step lt+1) and store ptr (step lt)
    const _Float16* Upf = Ub + Ustep;
    _Float16* Ust = Ub + k;            // q==1 lanes store h here each step
    float u2c = (float)Ub[k], u3c = (float)Ub[128 + k], u4c = (float)Ub[256 + k];

#define SCAN_STAGE1()                                                                \
        float4 hq0 = hpv[q * 8 + 0], hq1 = hpv[q * 8 + 1],                           \
               hq2 = hpv[q * 8 + 2], hq3 = hpv[q * 8 + 3],                           \
               hq4 = hpv[q * 8 + 4], hq5 = hpv[q * 8 + 5],                           \
               hq6 = hpv[q * 8 + 6], hq7 = hpv[q * 8 + 7];                           \
        float s2a = 0.f, s2b = 0.f, s3a = 0.f, s3b = 0.f, s4a = 0.f, s4b = 0.f;      \
        DOT4(s2a, wA0, hq0); DOT4(s2b, wA1, hq1); DOT4(s2a, wA2, hq2); DOT4(s2b, wA3, hq3); \
        DOT4(s2a, wA4, hq4); DOT4(s2b, wA5, hq5); DOT4(s2a, wA6, hq6); DOT4(s2b, wA7, hq7); \
        DOT4(s3a, wB0, hq0); DOT4(s3b, wB1, hq1); DOT4(s3a, wB2, hq2); DOT4(s3b, wB3, hq3); \
        DOT4(s3a, wB4, hq4); DOT4(s3b, wB5, hq5); DOT4(s3a, wB6, hq6); DOT4(s3b, wB7, hq7); \
        DOT4(s4a, wC0, hq0); DOT4(s4b, wC1, hq1); DOT4(s4a, wC2, hq2); DOT4(s4b, wC3, hq3); \
        DOT4(s4a, wC4, hq4); DOT4(s4b, wC5, hq5); DOT4(s4a, wC6, hq6); DOT4(s4b, wC7, hq7); \
        float s2 = qsum1(s2a + s2b);                                                 \
        float s3 = qsum1(s3a + s3b);                                                 \
        float s4 = qsum1(s4a + s4b);                                                 \
        float LG_k = sigm(s3 + u3c) * sigm(2.f * (s2 + u2c));                        \
        if (q == 0) ((_Float16*)lgv)[k] = (_Float16)LG_k;                            \
        LBAR();

#define SCAN_STAGE2()                                                                \
        float4 lq0 = lgv[q * 8 + 0], lq1 = lgv[q * 8 + 1],                           \
               lq2 = lgv[q * 8 + 2], lq3 = lgv[q * 8 + 3];                           \
        float4 lq4 = lgv[q * 8 + 4], lq5 = lgv[q * 8 + 5],                           \
               lq6 = lgv[q * 8 + 6], lq7 = lgv[q * 8 + 7];                           \
        float sLa = 0.f, sLb = 0.f;                                                  \
        DOT4(sLa, wD0, lq0); DOT4(sLb, wD1, lq1); DOT4(sLa, wD2, lq2); DOT4(sLb, wD3, lq3); \
        DOT4(sLa, wD4, lq4); DOT4(sLb, wD5, lq5); DOT4(sLa, wD6, lq6); DOT4(sLb, wD7, lq7); \
        float s4l = qsum1(sLa + sLb);                                                \
        float gf = sigm(s4 + s4l + u4c);                                             \
        h_k = LG_k + gf * h_k;                                                       \
        if (q == 0) ((_Float16*)hpv)[k] = (_Float16)h_k;                             \
        if (q == 1) *Ust = (_Float16)h_k;                                            \
        LBAR();

    for (int lt = 0; lt < T_len - 1; ++lt) {
        // unconditional prefetch via carried pointer
        float u2n = (float)Upf[k];
        float u3n = (float)Upf[128 + k];
        float u4n = (float)Upf[256 + k];

        { SCAN_STAGE1() SCAN_STAGE2() }

        Ust += Ustep; Upf += Ustep;
        u2c = u2n; u3c = u3n; u4c = u4n;
    }
    // peeled final iteration (no prefetch)
    { SCAN_STAGE1() SCAN_STAGE2() }

#undef SCAN_STAGE1
#undef SCAN_STAGE2

    if (q == 0) hcarry[b * 128 + k] = h_k;
}

// ---------------- MFMA GEMM 3 + fused readout: ability/term/y ---------------------
__global__ __launch_bounds__(256) void k_mm_a(
    const _Float16* __restrict__ U16, const _Float16* __restrict__ diff16,
    const float* __restrict__ disc, const _Float16* __restrict__ Wa16,
    const float* __restrict__ ba, float* __restrict__ pred, int t0)
{
    __shared__ _Float16 smem[2][128 * 64];   // A/B tiles; later d-tile [128][128]
    __shared__ float redbuf[128][2];
    __shared__ float baS[128];
    __shared__ float gS[128];

    const int tid = threadIdx.x;
    const int ur0 = blockIdx.x * 128;
    const int lt = ur0 >> 8;
    _Float16* As = smem[0];
    _Float16* Bs = smem[1];

    if (tid < 128) {
        baS[tid] = ba[tid];
        int r = ur0 + tid;
        int b = r & 255;
        gS[tid] = disc[b * S_LEN + t0 + lt + 1];
    }

    const int wid = tid >> 6, lane = tid & 63;
    const int wr = wid >> 1, wc = wid & 1;
    const int lrow = lane & 15, lkg = lane >> 4;
    const int arow = tid >> 1, apart = tid & 1;

    f32x4 acc[4][4];
#pragma unroll
    for (int i = 0; i < 4; ++i)
#pragma unroll
        for (int j = 0; j < 4; ++j) acc[i][j] = (f32x4){0.f, 0.f, 0.f, 0.f};

    for (int kb = 0; kb < 2; ++kb) {
        int k0 = kb * 64;
        const _Float16* srcA = U16 + (size_t)(ur0 + arow) * 384 + k0 + apart * 32;
        const _Float16* srcB = Wa16 + (size_t)arow * 128 + k0 + apart * 32;
#pragma unroll
        for (int j = 0; j < 4; ++j) {
            float4 va = *(const float4*)(srcA + j * 8);
            float4 vb = *(const float4*)(srcB + j * 8);
            int boff = apart * 64 + j * 16;
            *(float4*)((char*)As + swz(arow, boff)) = va;
            *(float4*)((char*)Bs + swz(arow, boff)) = vb;
        }
        __syncthreads();
#pragma unroll
        for (int ks = 0; ks < 2; ++ks) {
            f16x8 af[4], bf[4];
#pragma unroll
            for (int f = 0; f < 4; ++f) {
                int ar = wr * 64 + f * 16 + lrow;
                af[f] = *(const f16x8*)((const char*)As + swz(ar, ks * 64 + lkg * 16));
                int br = wc * 64 + f * 16 + lrow;
                bf[f] = *(const f16x8*)((const char*)Bs + swz(br, ks * 64 + lkg * 16));
            }
#pragma unroll
            for (int fi = 0; fi < 4; ++fi)
#pragma unroll
                for (int fj = 0; fj < 4; ++fj)
                    acc[fi][fj] = __builtin_amdgcn_mfma_f32_16x16x32_f16(
                        af[fi], bf[fj], acc[fi][fj], 0, 0, 0);
        }
        __syncthreads();
    }

    // stage d tile [128 rows][128 cols] into smem (32 KB, coalesced)
    {
        const float4* dsrc = (const float4*)(diff16 + (size_t)(ur0 + 512) * 128);
        float4* ddst = (float4*)smem;
        for (int i = tid; i < 2048; i += 256) ddst[i] = dsrc[i];
    }
    __syncthreads();

    const _Float16* dtile = (const _Float16*)smem;
#pragma unroll
    for (int fi = 0; fi < 4; ++fi) {
#pragma unroll
        for (int rr = 0; rr < 4; ++rr) {
            int row = wr * 64 + fi * 16 + (lane >> 4) * 4 + rr;
            float part = 0.f;
#pragma unroll
            for (int fj = 0; fj < 4; ++fj) {
                int col = wc * 64 + fj * 16 + (lane & 15);
                float d = (float)dtile[row * 128 + col];
                float ab = sigm(acc[fi][fj][rr] + baS[col]);
                part += (ab - d) * d;
            }
            part += __shfl_xor(part, 1, 64);
            part += __shfl_xor(part, 2, 64);
            part += __shfl_xor(part, 4, 64);
            part += __shfl_xor(part, 8, 64);
            if ((lane & 15) == 0) redbuf[row][wc] = part;
        }
    }
    __syncthreads();
    if (tid < 128) {
        int r = ur0 + tid;
        int b = r & 255;
        float v = redbuf[tid][0] + redbuf[tid][1];
        pred[(size_t)b * S_LEN + t0 + lt + 1] = sigm(gS[tid] * v);
    }
}

extern "C" void kernel_launch(void* const* d_in, const int* in_sizes, int n_in,
                              void* d_out, int out_size, void* d_ws, size_t ws_size,
                              hipStream_t stream)
{
    const int*   qseq  = (const int*)d_in[0];
    const int*   itseq = (const int*)d_in[1];
    const int*   utseq = (const int*)d_in[2];
    const int*   cseq  = (const int*)d_in[3];
    const float* h0    = (const float*)d_in[4];
    const float* Eq    = (const float*)d_in[5];
    const float* Eut   = (const float*)d_in[6];
    const float* Eit   = (const float*)d_in[7];
    const float* W1    = (const float*)d_in[8];
    const float* b1    = (const float*)d_in[9];
    const float* W2    = (const float*)d_in[10];
    const float* b2    = (const float*)d_in[11];
    const float* W3    = (const float*)d_in[12];
    const float* b3    = (const float*)d_in[13];
    const float* W4    = (const float*)d_in[14];
    const float* b4    = (const float*)d_in[15];
    const float* Wa    = (const float*)d_in[16];
    const float* ba    = (const float*)d_in[17];
    const float* Wd    = (const float*)d_in[18];
    const float* bd    = (const float*)d_in[19];
    const float* Wdisc = (const float*)d_in[20];
    const float* bdisc = (const float*)d_in[21];
    float* pred = (float*)d_out;

    // --- fixed-region layout ---
    char* p = (char*)d_ws;
    float* bz      = (float*)p;           p += 384 * 4;
    float* w1csum  = (float*)p;           p += 128 * 4;
    float* discb   = (float*)p;           p += 131072 * 4;
    float* hcarry  = (float*)p;           p += 32768 * 4;
    _Float16* Eq16  = (_Float16*)p;       p += 10001 * 128 * 2;
    _Float16* Eut16 = (_Float16*)p;       p += 1025 * 128 * 2;
    _Float16* Eit16 = (_Float16*)p;       p += 1025 * 128 * 2;
    _Float16* Wld16 = (_Float16*)p;       p += 256 * 256 * 2;
    _Float16* Wz16  = (_Float16*)p;       p += 384 * 384 * 2;
    _Float16* Wa16  = (_Float16*)p;       p += 128 * 128 * 2;
    h2*       Wsc   = (h2*)p;             p += 256 * 128 * 4;   // 128 KB
    const size_t fixed_bytes = (size_t)(p - (char*)d_ws);

    int T_CH = 4;
    {
        const int cands[8] = {511, 256, 128, 64, 32, 16, 8, 4};
        for (int ci = 0; ci < 8; ++ci) {
            size_t T = (size_t)cands[ci];
            size_t need = fixed_bytes + (T + 2) * 131072 + T * 196608;
            if (need <= ws_size) { T_CH = cands[ci]; break; }
        }
    }
    _Float16* learn16 = (_Float16*)p;     p += (size_t)(T_CH + 2) * 65536 * 2;
    _Float16* diff16  = (_Float16*)p;     p += (size_t)(T_CH + 2) * 65536 * 2;
    _Float16* U16     = (_Float16*)p;

    k_pack16<<<2048, 256, 0, stream>>>(W1, Wd, W2, W3, W4, b2, b3, b4, h0, Wa,
                                       Eq, Eut, Eit, qseq, Wdisc, bdisc,
                                       Eq16, Eut16, Eit16, Wld16, Wz16, Wa16, Wsc,
                                       bz, w1csum, hcarry, pred, discb);

    for (int t0 = 0; t0 < S_LEN - 1; t0 += T_CH) {
        int T_len = S_LEN - 1 - t0; if (T_len > T_CH) T_len = T_CH;
        int s_lo = (t0 == 0) ? 0 : (t0 - 1);
        int s_hi = t0 + T_len + 1;
        int out_row0 = (s_lo - (t0 - 1)) * 256;
        k_mm_ld<<<dim3((s_hi - s_lo) * 2, 2), 256, 0, stream>>>(
            qseq, utseq, cseq, Eq16, Eut16, Wld16, b1, bd, w1csum,
            learn16, diff16, s_lo, out_row0);
        k_mm_u<<<dim3(T_len * 2, 3), 256, 0, stream>>>(
            itseq, Eit16, learn16, Wz16, bz, U16, t0);
        k_scan<<<256, 256, 0, stream>>>(U16, hcarry, Wsc, T_len);
        k_mm_a<<<T_len * 2, 256, 0, stream>>>(U16, diff16, discb, Wa16, ba, pred, t0);
    }
}